// Round 14
// baseline (292.248 us; speedup 1.0000x reference)
//
#include <hip/hip_runtime.h>
#include <hip/hip_bf16.h>

#define Nn 50000
#define Ee 600000
#define Dd 128
#define EPSc 1e-5f
#define GX 391   // gemm grid: ceil(50000/128)
#define NB 196   // scan tiles: ceil(50000/256)

typedef unsigned int u32;
typedef unsigned short u16;
typedef short s16x8 __attribute__((ext_vector_type(8)));
typedef float f32x4 __attribute__((ext_vector_type(4)));

__device__ inline float bf2f(u32 lo16) { return __uint_as_float(lo16 << 16); }
__device__ inline u16 f2bf(float f) {
    u32 b = __float_as_uint(f);
    return (u16)((b + 0x7fffu + ((b >> 16) & 1u)) >> 16);  // RTN-even
}
__device__ inline void gload16(const void* g, void* l) {
    __builtin_amdgcn_global_load_lds(
        (const __attribute__((address_space(1))) u32*)g,
        (__attribute__((address_space(3))) u32*)l, 16, 0, 0);
}

// ---------------- merged prologue: conv | hist | wprep2 ----------------------
// blocks [0,1024): feat fp32 -> x16 bf16 (grid-stride over Nn*32 float4)
// blocks [1024,3368): histogram of dst into cnt (2344 blocks)
// blocks [3368,4008): Wt[l][c][k] bf16, k: V(512)|loop(128) (640 blocks)
__global__ __launch_bounds__(256) void prep_k(const float* __restrict__ feat,
                                              const int* __restrict__ dst,
                                              const float* __restrict__ V0,
                                              const float* __restrict__ loop0,
                                              const float* __restrict__ V1,
                                              const float* __restrict__ loop1,
                                              u16* __restrict__ x16,
                                              int* __restrict__ cnt,
                                              u16* __restrict__ Wt) {
    const int b = blockIdx.x, tid = threadIdx.x;
    if (b < 1024) {
        const int total = Nn * 32;
        for (int i = b * 256 + tid; i < total; i += 1024 * 256) {
            float4 v = ((const float4*)feat)[i];
            ((ushort4*)x16)[i] =
                make_ushort4(f2bf(v.x), f2bf(v.y), f2bf(v.z), f2bf(v.w));
        }
    } else if (b < 3368) {
        int e = (b - 1024) * 256 + tid;
        if (e < Ee) atomicAdd(&cnt[dst[e]], 1);
    } else {
        int i = (b - 3368) * 256 + tid;  // < 163840
        int l = i / 81920, r = i - l * 81920;
        int c = r / 640, k = r - c * 640;
        const float* V = l ? V1 : V0;
        const float* lp = l ? loop1 : loop0;
        float v = (k < 512) ? V[(size_t)k * 128 + c]
                            : lp[(size_t)(k - 512) * 128 + c];
        Wt[i] = f2bf(v);
    }
}

// ---------------- 3-pass scan ----------------
__global__ __launch_bounds__(256) void scanA_k(const int* __restrict__ cnt,
                                               int* __restrict__ rowp,
                                               int* __restrict__ bsum) {
    __shared__ int ws4[4];
    const int tid = threadIdx.x, lane = tid & 63, w = tid >> 6;
    const int i = blockIdx.x * 256 + tid;
    int v = (i < Nn) ? cnt[i] : 0;
    int incl = v;
#pragma unroll
    for (int off = 1; off < 64; off <<= 1) {
        int u = __shfl_up(incl, off, 64);
        if (lane >= off) incl += u;
    }
    if (lane == 63) ws4[w] = incl;
    __syncthreads();
    if (tid == 0) {
        int run = 0;
#pragma unroll
        for (int j = 0; j < 4; j++) { int s = ws4[j]; ws4[j] = run; run += s; }
    }
    __syncthreads();
    incl += ws4[w];
    if (i < Nn) rowp[i + 1] = incl;
    if (tid == 255) bsum[blockIdx.x] = incl;
}

__global__ __launch_bounds__(256) void scanB_k(const int* __restrict__ bsum,
                                               int* __restrict__ boff) {
    __shared__ int ws4[4];
    const int tid = threadIdx.x, lane = tid & 63, w = tid >> 6;
    int v = (tid < NB) ? bsum[tid] : 0;
    int incl = v;
#pragma unroll
    for (int off = 1; off < 64; off <<= 1) {
        int u = __shfl_up(incl, off, 64);
        if (lane >= off) incl += u;
    }
    if (lane == 63) ws4[w] = incl;
    __syncthreads();
    if (tid == 0) {
        int run = 0;
#pragma unroll
        for (int j = 0; j < 4; j++) { int s = ws4[j]; ws4[j] = run; run += s; }
    }
    __syncthreads();
    if (tid < NB) boff[tid] = incl + ws4[w] - v;  // exclusive
}

// adds block offsets; also seeds the scatter cursor (cursor[i] = rowp[i])
__global__ __launch_bounds__(256) void scanC_k(const int* __restrict__ boff,
                                               int* __restrict__ rowp,
                                               int* __restrict__ cursor) {
    const int i = blockIdx.x * 256 + threadIdx.x;
    if (i < Nn) {
        int v = rowp[i + 1] + boff[blockIdx.x];
        rowp[i + 1] = v;
        if (i + 1 < Nn) cursor[i + 1] = v;
    }
    if (i == 0) { rowp[0] = 0; cursor[0] = 0; }
}

__global__ __launch_bounds__(256) void scatter_k(const int* __restrict__ src,
                                                 const int* __restrict__ dst,
                                                 const int* __restrict__ et,
                                                 int* __restrict__ cursor,
                                                 int2* __restrict__ se) {
    int e = blockIdx.x * 256 + threadIdx.x;
    if (e < Ee) {
        int pos = atomicAdd(&cursor[dst[e]], 1);
        se[pos] = make_int2(src[e], et[e]);
    }
}

// ---------------- aggregation: yb16[n,b,:] = sum_e comb[et,b]*x16[src] -------
// R6-proven structure: 1 node/wave, 4-deep MLP chunks, tail zero-masked.
// Bound by per-CU gather line rate; depth-4 minimizes slot waste (R10/R11:
// depth-8 and dual-chain both regressed).
__global__ __launch_bounds__(256) void agg_k(const u16* __restrict__ x16,
                                             const int2* __restrict__ se,
                                             const int* __restrict__ rowp,
                                             const float* __restrict__ comb,
                                             u16* __restrict__ yb16) {
    const int node = blockIdx.x * 4 + (threadIdx.x >> 6);
    const int lane = threadIdx.x & 63;
    const int beg = rowp[node], end = rowp[node + 1];
    float a0x = 0.f, a0y = 0.f, a1x = 0.f, a1y = 0.f;
    float a2x = 0.f, a2y = 0.f, a3x = 0.f, a3y = 0.f;
    const int eL = end - 1;
    const int co = lane * 2;

    for (int e0 = beg; e0 < end; e0 += 4) {
        const int m = end - e0;
        const int2 rc0 = se[e0];
        const int2 rc1 = se[min(e0 + 1, eL)];
        const int2 rc2 = se[min(e0 + 2, eL)];
        const int2 rc3 = se[min(e0 + 3, eL)];
        u32 x0 = *(const u32*)&x16[(size_t)rc0.x * 128 + co];
        u32 x1 = *(const u32*)&x16[(size_t)rc1.x * 128 + co];
        u32 x2 = *(const u32*)&x16[(size_t)rc2.x * 128 + co];
        u32 x3 = *(const u32*)&x16[(size_t)rc3.x * 128 + co];
        if (m < 4) x3 = 0;
        if (m < 3) x2 = 0;
        if (m < 2) x1 = 0;
        const float4 c0 = ((const float4*)comb)[rc0.y];
        const float4 c1 = ((const float4*)comb)[rc1.y];
        const float4 c2 = ((const float4*)comb)[rc2.y];
        const float4 c3 = ((const float4*)comb)[rc3.y];
#define ACC1(c, xv)                                        \
        {                                                  \
            const float fx = bf2f((xv) & 0xffffu);         \
            const float fy = bf2f((xv) >> 16);             \
            a0x += c.x * fx; a0y += c.x * fy;              \
            a1x += c.y * fx; a1y += c.y * fy;              \
            a2x += c.z * fx; a2y += c.z * fy;              \
            a3x += c.w * fx; a3y += c.w * fy;              \
        }
        ACC1(c0, x0)
        ACC1(c1, x1)
        ACC1(c2, x2)
        ACC1(c3, x3)
#undef ACC1
    }
    u32* yp = (u32*)(yb16 + (size_t)node * 512);
    yp[lane]       = (u32)f2bf(a0x) | ((u32)f2bf(a0y) << 16);
    yp[64 + lane]  = (u32)f2bf(a1x) | ((u32)f2bf(a1y) << 16);
    yp[128 + lane] = (u32)f2bf(a2x) | ((u32)f2bf(a2y) << 16);
    yp[192 + lane] = (u32)f2bf(a3x) | ((u32)f2bf(a3y) << 16);
}

// ---------------- MFMA GEMM: h16 = relu([yb16|x16] @ Wt^T + bias) (bf16 out) -
// BM=128,BN=128,BK=32, 4 waves (2x2 of 64x64), single 16KB LDS buffer.
// Epilogue: bf16 h store; per-block column partials (sum|sumsq from fp32
// regs) -> plain stores, NO atomics (R9: stats atomics cost ~33us/layer).
__global__ __launch_bounds__(256) void gemm_mfma_k(const u16* __restrict__ yb16,
                                                   const u16* __restrict__ x16,
                                                   const u16* __restrict__ Wt,
                                                   const float* __restrict__ bias,
                                                   u16* __restrict__ H16,
                                                   float* __restrict__ partials) {
    __shared__ __align__(16) char As[8192];  // 128 rows x 64 B
    __shared__ __align__(16) char Bs[8192];  // 128 cols x 64 B
    const int tid = threadIdx.x;
    const int lane = tid & 63, wid = tid >> 6;
    const int wr = wid >> 1, wc = wid & 1;
    const int bm = blockIdx.x * 128;

    f32x4 acc[4][4] = {};

    const int r0 = wid * 32;
    const int lrow = lane >> 2;
    const int sphys = lane & 3;
    const int rowL0 = r0 + lrow, rowL1 = r0 + 16 + lrow;
    const int slog0 = (sphys ^ ((rowL0 >> 1) & 3)) * 8;
    const int slog1 = (sphys ^ ((rowL1 >> 1) & 3)) * 8;
    int ga0 = bm + rowL0; if (ga0 >= Nn) ga0 = Nn - 1;
    int ga1 = bm + rowL1; if (ga1 >= Nn) ga1 = Nn - 1;

    for (int k0 = 0; k0 < 640; k0 += 32) {
        __syncthreads();
        const u16 *as0, *as1;
        if (k0 < 512) {
            as0 = yb16 + (size_t)ga0 * 512 + k0 + slog0;
            as1 = yb16 + (size_t)ga1 * 512 + k0 + slog1;
        } else {
            as0 = x16 + (size_t)ga0 * 128 + (k0 - 512) + slog0;
            as1 = x16 + (size_t)ga1 * 128 + (k0 - 512) + slog1;
        }
        gload16(as0, &As[r0 * 64]);
        gload16(as1, &As[(r0 + 16) * 64]);
        gload16(Wt + (size_t)rowL0 * 640 + k0 + slog0, &Bs[r0 * 64]);
        gload16(Wt + (size_t)rowL1 * 640 + k0 + slog1, &Bs[(r0 + 16) * 64]);
        __syncthreads();
        s16x8 a[4], b[4];
#pragma unroll
        for (int m = 0; m < 4; m++) {
            int row = wr * 64 + m * 16 + (lane & 15);
            a[m] = *(const s16x8*)&As[row * 64 + (((lane >> 4) ^ ((row >> 1) & 3)) << 4)];
            int col = wc * 64 + m * 16 + (lane & 15);
            b[m] = *(const s16x8*)&Bs[col * 64 + (((lane >> 4) ^ ((col >> 1) & 3)) << 4)];
        }
#pragma unroll
        for (int m = 0; m < 4; m++)
#pragma unroll
            for (int n = 0; n < 4; n++)
                acc[m][n] = __builtin_amdgcn_mfma_f32_16x16x32_bf16(a[m], b[n],
                                                                    acc[m][n], 0, 0, 0);
    }
    float bv[4], cs[4] = {}, cq[4] = {};
#pragma unroll
    for (int n = 0; n < 4; n++) bv[n] = bias[wc * 64 + n * 16 + (lane & 15)];
#pragma unroll
    for (int m = 0; m < 4; m++) {
        const int rb = bm + wr * 64 + m * 16 + ((lane >> 4) << 2);
#pragma unroll
        for (int e = 0; e < 4; e++) {
            const int r = rb + e;
            if (r < Nn) {
                u16* hp = H16 + (size_t)r * 128 + wc * 64 + (lane & 15);
#pragma unroll
                for (int n = 0; n < 4; n++) {
                    float v = fmaxf(acc[m][n][e] + bv[n], 0.f);
                    hp[n * 16] = f2bf(v);
                    cs[n] += v;
                    cq[n] += v * v;
                }
            }
        }
    }
#pragma unroll
    for (int n = 0; n < 4; n++) {
        cs[n] += __shfl_xor(cs[n], 16);
        cs[n] += __shfl_xor(cs[n], 32);
        cq[n] += __shfl_xor(cq[n], 16);
        cq[n] += __shfl_xor(cq[n], 32);
    }
    __syncthreads();
    float* red = (float*)As;
    if (wr == 1 && lane < 16) {
#pragma unroll
        for (int n = 0; n < 4; n++) {
            const int col = wc * 64 + n * 16 + lane;
            red[col] = cs[n];
            red[128 + col] = cq[n];
        }
    }
    __syncthreads();
    if (wr == 0 && lane < 16) {
        float* pp = partials + (size_t)blockIdx.x * 256;
#pragma unroll
        for (int n = 0; n < 4; n++) {
            const int col = wc * 64 + n * 16 + lane;
            pp[col] = cs[n] + red[col];
            pp[128 + col] = cq[n] + red[128 + col];
        }
    }
}

// ---------------- partials reduce: 1 block x 1024 thr, 4-way row split -------
__global__ __launch_bounds__(1024) void red_k(const float* __restrict__ partials,
                                              float* __restrict__ stats) {
    __shared__ float part[4][256];
    const int c = threadIdx.x & 255, g = threadIdx.x >> 8;
    float s = 0.f;
    for (int b = g; b < GX; b += 4) s += partials[(size_t)b * 256 + c];
    part[g][c] = s;
    __syncthreads();
    if (g == 0)
        stats[c] = (part[0][c] + part[1][c]) + (part[2][c] + part[3][c]);
}

// ---------------- BN normalize from bf16 h; outputs optional ----------------
__global__ __launch_bounds__(256) void norm_k(const u16* __restrict__ h16,
                                              const float* __restrict__ stats,
                                              const float* __restrict__ gamma,
                                              const float* __restrict__ beta,
                                              float* __restrict__ outp,
                                              u16* __restrict__ xb16) {
    const float invN = 1.0f / (float)Nn;
    int total = Nn * 32;
    for (int i = blockIdx.x * blockDim.x + threadIdx.x; i < total;
         i += gridDim.x * blockDim.x) {
        int c = (i & 31) * 4;
        ushort4 hv = ((const ushort4*)h16)[i];
        float4 o;
        {
            float mu = stats[c + 0] * invN;
            float var = stats[Dd + c + 0] * invN - mu * mu;
            o.x = gamma[c + 0] * (bf2f(hv.x) - mu) * rsqrtf(var + EPSc) + beta[c + 0];
        }
        {
            float mu = stats[c + 1] * invN;
            float var = stats[Dd + c + 1] * invN - mu * mu;
            o.y = gamma[c + 1] * (bf2f(hv.y) - mu) * rsqrtf(var + EPSc) + beta[c + 1];
        }
        {
            float mu = stats[c + 2] * invN;
            float var = stats[Dd + c + 2] * invN - mu * mu;
            o.z = gamma[c + 2] * (bf2f(hv.z) - mu) * rsqrtf(var + EPSc) + beta[c + 2];
        }
        {
            float mu = stats[c + 3] * invN;
            float var = stats[Dd + c + 3] * invN - mu * mu;
            o.w = gamma[c + 3] * (bf2f(hv.w) - mu) * rsqrtf(var + EPSc) + beta[c + 3];
        }
        if (outp) ((float4*)outp)[i] = o;
        if (xb16) ((ushort4*)xb16)[i] = make_ushort4(f2bf(o.x), f2bf(o.y),
                                                     f2bf(o.z), f2bf(o.w));
    }
}

// ---------------- launch ----------------
extern "C" void kernel_launch(void* const* d_in, const int* in_sizes, int n_in,
                              void* d_out, int out_size, void* d_ws, size_t ws_size,
                              hipStream_t stream) {
    const float* feat = (const float*)d_in[0];
    const int* src = (const int*)d_in[1];
    const int* dst = (const int*)d_in[2];
    const int* et = (const int*)d_in[3];
    float* out = (float*)d_out;

    // workspace (~83 MB)
    char* p = (char*)d_ws;
    u16* yb16 = (u16*)p;     p += (size_t)Nn * 512 * 2;                  // 51.2 MB
    u16* x16 = (u16*)p;      p += (size_t)Nn * 128 * 2;                  // 12.8 MB
    u16* h16 = (u16*)p;      p += (size_t)Nn * 128 * 2;                  // 12.8 MB
    u16* Wt = (u16*)p;       p += (size_t)2 * 128 * 640 * 2;             // 320 KB
    int* rowp = (int*)p;     p += ((((size_t)(Nn + 1) * 4) + 15) & ~15ull);
    int2* se = (int2*)p;     p += (size_t)Ee * 8;                        // 4.8 MB
    float* partials = (float*)p;  p += (size_t)GX * 256 * 4;             // 400 KB
    float* stats = (float*)p;     p += 2 * Dd * 4;
    int* bsum = (int*)p;          p += ((NB * 4 + 15) & ~15);
    int* boff = (int*)p;          p += ((NB * 4 + 15) & ~15);
    int* cursor = (int*)yb16;  // dead before agg_k writes yb16

    // ---- prologue: conv | hist | wprep merged; then scans + scatter ----
    hipMemsetAsync(cursor, 0, (size_t)Nn * 4, stream);
    prep_k<<<4008, 256, 0, stream>>>(feat, dst,
                                     (const float*)d_in[4], (const float*)d_in[6],
                                     (const float*)d_in[10], (const float*)d_in[12],
                                     x16, cursor, Wt);
    scanA_k<<<NB, 256, 0, stream>>>(cursor, rowp, bsum);
    scanB_k<<<1, 256, 0, stream>>>(bsum, boff);
    scanC_k<<<NB, 256, 0, stream>>>(boff, rowp, cursor);
    scatter_k<<<(Ee + 255) / 256, 256, 0, stream>>>(src, dst, et, cursor, se);

    for (int l = 0; l < 2; l++) {
        const float* comb = (const float*)d_in[4 + 6 * l + 1];
        const float* bias = (const float*)d_in[4 + 6 * l + 3];
        const float* gamma = (const float*)d_in[4 + 6 * l + 4];
        const float* beta = (const float*)d_in[4 + 6 * l + 5];

        agg_k<<<Nn / 4, 256, 0, stream>>>(x16, se, rowp, comb, yb16);
        gemm_mfma_k<<<GX, 256, 0, stream>>>(yb16, x16, Wt + (size_t)l * 81920,
                                            bias, h16, partials);
        red_k<<<1, 1024, 0, stream>>>(partials, stats);
        norm_k<<<2048, 256, 0, stream>>>(h16, stats, gamma, beta,
                                         (l == 0) ? nullptr : out,
                                         (l == 0) ? x16 : nullptr);
    }
}

// Round 15
// 260.709 us; speedup vs baseline: 1.1210x; 1.1210x over previous
//
#include <hip/hip_runtime.h>
#include <hip/hip_bf16.h>

#define Nn 50000
#define Ee 600000
#define Dd 128
#define EPSc 1e-5f
#define GX 391   // gemm grid: ceil(50000/128)
#define NB 196   // scan tiles: ceil(50000/256)

typedef unsigned int u32;
typedef unsigned short u16;
typedef short s16x8 __attribute__((ext_vector_type(8)));
typedef float f32x4 __attribute__((ext_vector_type(4)));

__device__ inline float bf2f(u32 lo16) { return __uint_as_float(lo16 << 16); }
__device__ inline u16 f2bf(float f) {
    u32 b = __float_as_uint(f);
    return (u16)((b + 0x7fffu + ((b >> 16) & 1u)) >> 16);  // RTN-even
}
__device__ inline void gload16(const void* g, void* l) {
    __builtin_amdgcn_global_load_lds(
        (const __attribute__((address_space(1))) u32*)g,
        (__attribute__((address_space(3))) u32*)l, 16, 0, 0);
}

// ---------------- merged prologue: conv | hist | wprep2 ----------------------
__global__ __launch_bounds__(256) void prep_k(const float* __restrict__ feat,
                                              const int* __restrict__ dst,
                                              const float* __restrict__ V0,
                                              const float* __restrict__ loop0,
                                              const float* __restrict__ V1,
                                              const float* __restrict__ loop1,
                                              u16* __restrict__ x16,
                                              int* __restrict__ cnt,
                                              u16* __restrict__ Wt) {
    const int b = blockIdx.x, tid = threadIdx.x;
    if (b < 1024) {
        const int total = Nn * 32;
        for (int i = b * 256 + tid; i < total; i += 1024 * 256) {
            float4 v = ((const float4*)feat)[i];
            ((ushort4*)x16)[i] =
                make_ushort4(f2bf(v.x), f2bf(v.y), f2bf(v.z), f2bf(v.w));
        }
    } else if (b < 3368) {
        int e = (b - 1024) * 256 + tid;
        if (e < Ee) atomicAdd(&cnt[dst[e]], 1);
    } else {
        int i = (b - 3368) * 256 + tid;  // < 163840
        int l = i / 81920, r = i - l * 81920;
        int c = r / 640, k = r - c * 640;
        const float* V = l ? V1 : V0;
        const float* lp = l ? loop1 : loop0;
        float v = (k < 512) ? V[(size_t)k * 128 + c]
                            : lp[(size_t)(k - 512) * 128 + c];
        Wt[i] = f2bf(v);
    }
}

// ---------------- 3-pass scan ----------------
__global__ __launch_bounds__(256) void scanA_k(const int* __restrict__ cnt,
                                               int* __restrict__ rowp,
                                               int* __restrict__ bsum) {
    __shared__ int ws4[4];
    const int tid = threadIdx.x, lane = tid & 63, w = tid >> 6;
    const int i = blockIdx.x * 256 + tid;
    int v = (i < Nn) ? cnt[i] : 0;
    int incl = v;
#pragma unroll
    for (int off = 1; off < 64; off <<= 1) {
        int u = __shfl_up(incl, off, 64);
        if (lane >= off) incl += u;
    }
    if (lane == 63) ws4[w] = incl;
    __syncthreads();
    if (tid == 0) {
        int run = 0;
#pragma unroll
        for (int j = 0; j < 4; j++) { int s = ws4[j]; ws4[j] = run; run += s; }
    }
    __syncthreads();
    incl += ws4[w];
    if (i < Nn) rowp[i + 1] = incl;
    if (tid == 255) bsum[blockIdx.x] = incl;
}

__global__ __launch_bounds__(256) void scanB_k(const int* __restrict__ bsum,
                                               int* __restrict__ boff) {
    __shared__ int ws4[4];
    const int tid = threadIdx.x, lane = tid & 63, w = tid >> 6;
    int v = (tid < NB) ? bsum[tid] : 0;
    int incl = v;
#pragma unroll
    for (int off = 1; off < 64; off <<= 1) {
        int u = __shfl_up(incl, off, 64);
        if (lane >= off) incl += u;
    }
    if (lane == 63) ws4[w] = incl;
    __syncthreads();
    if (tid == 0) {
        int run = 0;
#pragma unroll
        for (int j = 0; j < 4; j++) { int s = ws4[j]; ws4[j] = run; run += s; }
    }
    __syncthreads();
    if (tid < NB) boff[tid] = incl + ws4[w] - v;  // exclusive
}

// adds block offsets; also seeds the scatter cursor (cursor[i] = rowp[i])
__global__ __launch_bounds__(256) void scanC_k(const int* __restrict__ boff,
                                               int* __restrict__ rowp,
                                               int* __restrict__ cursor) {
    const int i = blockIdx.x * 256 + threadIdx.x;
    if (i < Nn) {
        int v = rowp[i + 1] + boff[blockIdx.x];
        rowp[i + 1] = v;
        if (i + 1 < Nn) cursor[i + 1] = v;
    }
    if (i == 0) { rowp[0] = 0; cursor[0] = 0; }
}

// se record: src (16b) | etype<<16  (N=50000<2^16, R=100<2^7)
__global__ __launch_bounds__(256) void scatter_k(const int* __restrict__ src,
                                                 const int* __restrict__ dst,
                                                 const int* __restrict__ et,
                                                 int* __restrict__ cursor,
                                                 u32* __restrict__ se) {
    int e = blockIdx.x * 256 + threadIdx.x;
    if (e < Ee) {
        int pos = atomicAdd(&cursor[dst[e]], 1);
        se[pos] = (u32)src[e] | ((u32)et[e] << 16);
    }
}

// ---------------- aggregation: yb16[n,b,:] = sum_e comb[et,b]*x16[src] -------
// 1 node/wave. Exact full-chunks of 4 (zero wasted gathers, no masking) +
// wave-uniform-guarded tail of <=3. Gather-request-throughput-bound (R10/R11:
// +20% duplicate requests cost +10-13% time), so waste removal is the lever.
__global__ __launch_bounds__(256) void agg_k(const u16* __restrict__ x16,
                                             const u32* __restrict__ se,
                                             const int* __restrict__ rowp,
                                             const float* __restrict__ comb,
                                             u16* __restrict__ yb16) {
    const int node = blockIdx.x * 4 + (threadIdx.x >> 6);
    const int lane = threadIdx.x & 63;
    const int beg = rowp[node], end = rowp[node + 1];
    float a0x = 0.f, a0y = 0.f, a1x = 0.f, a1y = 0.f;
    float a2x = 0.f, a2y = 0.f, a3x = 0.f, a3y = 0.f;
    const int co = lane * 2;

#define LOADX(r) (*(const u32*)&x16[(size_t)((r) & 0xffffu) * 128 + co])
#define CMB(r) (((const float4*)comb)[(r) >> 16])
#define ACC1(c, xv)                                        \
    {                                                      \
        const float fx = bf2f((xv) & 0xffffu);             \
        const float fy = bf2f((xv) >> 16);                 \
        a0x += c.x * fx; a0y += c.x * fy;                  \
        a1x += c.y * fx; a1y += c.y * fy;                  \
        a2x += c.z * fx; a2y += c.z * fy;                  \
        a3x += c.w * fx; a3y += c.w * fy;                  \
    }

    int e = beg;
    for (; e + 4 <= end; e += 4) {
        const u32 r0 = se[e], r1 = se[e + 1], r2 = se[e + 2], r3 = se[e + 3];
        const u32 x0 = LOADX(r0);
        const u32 x1 = LOADX(r1);
        const u32 x2 = LOADX(r2);
        const u32 x3 = LOADX(r3);
        const float4 c0 = CMB(r0);
        const float4 c1 = CMB(r1);
        const float4 c2 = CMB(r2);
        const float4 c3 = CMB(r3);
        ACC1(c0, x0)
        ACC1(c1, x1)
        ACC1(c2, x2)
        ACC1(c3, x3)
    }
    const int m = end - e;  // 0..3, wave-uniform
    if (m > 0) {
        const u32 r0 = se[e];
        u32 r1 = 0, r2 = 0;
        if (m > 1) r1 = se[e + 1];
        if (m > 2) r2 = se[e + 2];
        const u32 x0 = LOADX(r0);
        u32 x1 = 0, x2 = 0;
        if (m > 1) x1 = LOADX(r1);
        if (m > 2) x2 = LOADX(r2);
        const float4 c0 = CMB(r0);
        ACC1(c0, x0)
        if (m > 1) { const float4 c1 = CMB(r1); ACC1(c1, x1) }
        if (m > 2) { const float4 c2 = CMB(r2); ACC1(c2, x2) }
    }
#undef ACC1
#undef CMB
#undef LOADX

    u32* yp = (u32*)(yb16 + (size_t)node * 512);
    yp[lane]       = (u32)f2bf(a0x) | ((u32)f2bf(a0y) << 16);
    yp[64 + lane]  = (u32)f2bf(a1x) | ((u32)f2bf(a1y) << 16);
    yp[128 + lane] = (u32)f2bf(a2x) | ((u32)f2bf(a2y) << 16);
    yp[192 + lane] = (u32)f2bf(a3x) | ((u32)f2bf(a3y) << 16);
}

// ---------------- MFMA GEMM: h16 = relu([yb16|x16] @ Wt^T + bias) (bf16 out) -
__global__ __launch_bounds__(256) void gemm_mfma_k(const u16* __restrict__ yb16,
                                                   const u16* __restrict__ x16,
                                                   const u16* __restrict__ Wt,
                                                   const float* __restrict__ bias,
                                                   u16* __restrict__ H16,
                                                   float* __restrict__ partials) {
    __shared__ __align__(16) char As[8192];  // 128 rows x 64 B
    __shared__ __align__(16) char Bs[8192];  // 128 cols x 64 B
    const int tid = threadIdx.x;
    const int lane = tid & 63, wid = tid >> 6;
    const int wr = wid >> 1, wc = wid & 1;
    const int bm = blockIdx.x * 128;

    f32x4 acc[4][4] = {};

    const int r0 = wid * 32;
    const int lrow = lane >> 2;
    const int sphys = lane & 3;
    const int rowL0 = r0 + lrow, rowL1 = r0 + 16 + lrow;
    const int slog0 = (sphys ^ ((rowL0 >> 1) & 3)) * 8;
    const int slog1 = (sphys ^ ((rowL1 >> 1) & 3)) * 8;
    int ga0 = bm + rowL0; if (ga0 >= Nn) ga0 = Nn - 1;
    int ga1 = bm + rowL1; if (ga1 >= Nn) ga1 = Nn - 1;

    for (int k0 = 0; k0 < 640; k0 += 32) {
        __syncthreads();
        const u16 *as0, *as1;
        if (k0 < 512) {
            as0 = yb16 + (size_t)ga0 * 512 + k0 + slog0;
            as1 = yb16 + (size_t)ga1 * 512 + k0 + slog1;
        } else {
            as0 = x16 + (size_t)ga0 * 128 + (k0 - 512) + slog0;
            as1 = x16 + (size_t)ga1 * 128 + (k0 - 512) + slog1;
        }
        gload16(as0, &As[r0 * 64]);
        gload16(as1, &As[(r0 + 16) * 64]);
        gload16(Wt + (size_t)rowL0 * 640 + k0 + slog0, &Bs[r0 * 64]);
        gload16(Wt + (size_t)rowL1 * 640 + k0 + slog1, &Bs[(r0 + 16) * 64]);
        __syncthreads();
        s16x8 a[4], b[4];
#pragma unroll
        for (int m = 0; m < 4; m++) {
            int row = wr * 64 + m * 16 + (lane & 15);
            a[m] = *(const s16x8*)&As[row * 64 + (((lane >> 4) ^ ((row >> 1) & 3)) << 4)];
            int col = wc * 64 + m * 16 + (lane & 15);
            b[m] = *(const s16x8*)&Bs[col * 64 + (((lane >> 4) ^ ((col >> 1) & 3)) << 4)];
        }
#pragma unroll
        for (int m = 0; m < 4; m++)
#pragma unroll
            for (int n = 0; n < 4; n++)
                acc[m][n] = __builtin_amdgcn_mfma_f32_16x16x32_bf16(a[m], b[n],
                                                                    acc[m][n], 0, 0, 0);
    }
    float bv[4], cs[4] = {}, cq[4] = {};
#pragma unroll
    for (int n = 0; n < 4; n++) bv[n] = bias[wc * 64 + n * 16 + (lane & 15)];
#pragma unroll
    for (int m = 0; m < 4; m++) {
        const int rb = bm + wr * 64 + m * 16 + ((lane >> 4) << 2);
#pragma unroll
        for (int e = 0; e < 4; e++) {
            const int r = rb + e;
            if (r < Nn) {
                u16* hp = H16 + (size_t)r * 128 + wc * 64 + (lane & 15);
#pragma unroll
                for (int n = 0; n < 4; n++) {
                    float v = fmaxf(acc[m][n][e] + bv[n], 0.f);
                    hp[n * 16] = f2bf(v);
                    cs[n] += v;
                    cq[n] += v * v;
                }
            }
        }
    }
#pragma unroll
    for (int n = 0; n < 4; n++) {
        cs[n] += __shfl_xor(cs[n], 16);
        cs[n] += __shfl_xor(cs[n], 32);
        cq[n] += __shfl_xor(cq[n], 16);
        cq[n] += __shfl_xor(cq[n], 32);
    }
    __syncthreads();
    float* red = (float*)As;
    if (wr == 1 && lane < 16) {
#pragma unroll
        for (int n = 0; n < 4; n++) {
            const int col = wc * 64 + n * 16 + lane;
            red[col] = cs[n];
            red[128 + col] = cq[n];
        }
    }
    __syncthreads();
    if (wr == 0 && lane < 16) {
        float* pp = partials + (size_t)blockIdx.x * 256;
#pragma unroll
        for (int n = 0; n < 4; n++) {
            const int col = wc * 64 + n * 16 + lane;
            pp[col] = cs[n] + red[col];
            pp[128 + col] = cq[n] + red[128 + col];
        }
    }
}

// ---------------- partials reduce: 1 block x 1024 thr, 4-way row split -------
__global__ __launch_bounds__(1024) void red_k(const float* __restrict__ partials,
                                              float* __restrict__ stats) {
    __shared__ float part[4][256];
    const int c = threadIdx.x & 255, g = threadIdx.x >> 8;
    float s = 0.f;
    for (int b = g; b < GX; b += 4) s += partials[(size_t)b * 256 + c];
    part[g][c] = s;
    __syncthreads();
    if (g == 0)
        stats[c] = (part[0][c] + part[1][c]) + (part[2][c] + part[3][c]);
}

// ---------------- BN normalize from bf16 h; outputs optional ----------------
__global__ __launch_bounds__(256) void norm_k(const u16* __restrict__ h16,
                                              const float* __restrict__ stats,
                                              const float* __restrict__ gamma,
                                              const float* __restrict__ beta,
                                              float* __restrict__ outp,
                                              u16* __restrict__ xb16) {
    const float invN = 1.0f / (float)Nn;
    int total = Nn * 32;
    for (int i = blockIdx.x * blockDim.x + threadIdx.x; i < total;
         i += gridDim.x * blockDim.x) {
        int c = (i & 31) * 4;
        ushort4 hv = ((const ushort4*)h16)[i];
        float4 o;
        {
            float mu = stats[c + 0] * invN;
            float var = stats[Dd + c + 0] * invN - mu * mu;
            o.x = gamma[c + 0] * (bf2f(hv.x) - mu) * rsqrtf(var + EPSc) + beta[c + 0];
        }
        {
            float mu = stats[c + 1] * invN;
            float var = stats[Dd + c + 1] * invN - mu * mu;
            o.y = gamma[c + 1] * (bf2f(hv.y) - mu) * rsqrtf(var + EPSc) + beta[c + 1];
        }
        {
            float mu = stats[c + 2] * invN;
            float var = stats[Dd + c + 2] * invN - mu * mu;
            o.z = gamma[c + 2] * (bf2f(hv.z) - mu) * rsqrtf(var + EPSc) + beta[c + 2];
        }
        {
            float mu = stats[c + 3] * invN;
            float var = stats[Dd + c + 3] * invN - mu * mu;
            o.w = gamma[c + 3] * (bf2f(hv.w) - mu) * rsqrtf(var + EPSc) + beta[c + 3];
        }
        if (outp) ((float4*)outp)[i] = o;
        if (xb16) ((ushort4*)xb16)[i] = make_ushort4(f2bf(o.x), f2bf(o.y),
                                                     f2bf(o.z), f2bf(o.w));
    }
}

// ---------------- launch ----------------
extern "C" void kernel_launch(void* const* d_in, const int* in_sizes, int n_in,
                              void* d_out, int out_size, void* d_ws, size_t ws_size,
                              hipStream_t stream) {
    const float* feat = (const float*)d_in[0];
    const int* src = (const int*)d_in[1];
    const int* dst = (const int*)d_in[2];
    const int* et = (const int*)d_in[3];
    float* out = (float*)d_out;

    // workspace (~80 MB)
    char* p = (char*)d_ws;
    u16* yb16 = (u16*)p;     p += (size_t)Nn * 512 * 2;                  // 51.2 MB
    u16* x16 = (u16*)p;      p += (size_t)Nn * 128 * 2;                  // 12.8 MB
    u16* h16 = (u16*)p;      p += (size_t)Nn * 128 * 2;                  // 12.8 MB
    u16* Wt = (u16*)p;       p += (size_t)2 * 128 * 640 * 2;             // 320 KB
    int* rowp = (int*)p;     p += ((((size_t)(Nn + 1) * 4) + 15) & ~15ull);
    u32* se = (u32*)p;       p += (size_t)Ee * 4;                        // 2.4 MB
    float* partials = (float*)p;  p += (size_t)GX * 256 * 4;             // 400 KB
    float* stats = (float*)p;     p += 2 * Dd * 4;
    int* bsum = (int*)p;          p += ((NB * 4 + 15) & ~15);
    int* boff = (int*)p;          p += ((NB * 4 + 15) & ~15);
    int* cursor = (int*)yb16;  // dead before agg_k writes yb16

    // ---- prologue: conv | hist | wprep merged; then scans + scatter ----
    hipMemsetAsync(cursor, 0, (size_t)Nn * 4, stream);
    prep_k<<<4008, 256, 0, stream>>>(feat, dst,
                                     (const float*)d_in[4], (const float*)d_in[6],
                                     (const float*)d_in[10], (const float*)d_in[12],
                                     x16, cursor, Wt);
    scanA_k<<<NB, 256, 0, stream>>>(cursor, rowp, bsum);
    scanB_k<<<1, 256, 0, stream>>>(bsum, boff);
    scanC_k<<<NB, 256, 0, stream>>>(boff, rowp, cursor);
    scatter_k<<<(Ee + 255) / 256, 256, 0, stream>>>(src, dst, et, cursor, se);

    for (int l = 0; l < 2; l++) {
        const float* comb = (const float*)d_in[4 + 6 * l + 1];
        const float* bias = (const float*)d_in[4 + 6 * l + 3];
        const float* gamma = (const float*)d_in[4 + 6 * l + 4];
        const float* beta = (const float*)d_in[4 + 6 * l + 5];

        agg_k<<<Nn / 4, 256, 0, stream>>>(x16, se, rowp, comb, yb16);
        gemm_mfma_k<<<GX, 256, 0, stream>>>(yb16, x16, Wt + (size_t)l * 81920,
                                            bias, h16, partials);
        red_k<<<1, 1024, 0, stream>>>(partials, stats);
        norm_k<<<2048, 256, 0, stream>>>(h16, stats, gamma, beta,
                                         (l == 0) ? nullptr : out,
                                         (l == 0) ? x16 : nullptr);
    }
}